// Round 1
// baseline (449.096 us; speedup 1.0000x reference)
//
#include <hip/hip_runtime.h>

// SOM forward: pairwise d2 = ||x||^2 - 2 x.w + ||w||^2, argmin over M -> (idx/128, idx%128).
// x_sq is row-constant -> argmin of (w_sq[m] - 2 * dot(x, w[m])).
// B=4096 rows, M=16384 codebook entries, F=256. fp32 vector-ALU GEMM + fused argmin.

#define B_ROWS 4096
#define M_COLS 16384
#define KF 256
#define BM 128
#define BN 128
#define KT 16
#define NCHUNK 16
#define MC (M_COLS / NCHUNK)   // 1024 cols per chunk
#define COLTILES (MC / BN)     // 8

// ---------------- kernel 1: w_sq ----------------
__global__ __launch_bounds__(256) void som_wsq(const float* __restrict__ wt,
                                               float* __restrict__ wsq) {
    int gw = (blockIdx.x * 256 + threadIdx.x) >> 6;   // one wave per codebook entry
    int lane = threadIdx.x & 63;
    if (gw >= M_COLS) return;
    const float4 v = *reinterpret_cast<const float4*>(wt + (size_t)gw * KF + lane * 4);
    float s = v.x * v.x + v.y * v.y + v.z * v.z + v.w * v.w;
#pragma unroll
    for (int off = 32; off > 0; off >>= 1) s += __shfl_down(s, off, 64);
    if (lane == 0) wsq[gw] = s;
}

// ---------------- kernel 2: fused GEMM + argmin ----------------
__global__ __launch_bounds__(256) void som_main(const float* __restrict__ xb,
                                                const float* __restrict__ wt,
                                                const float* __restrict__ wsq,
                                                unsigned long long* __restrict__ part) {
    __shared__ float As[KT][BM];   // k-major
    __shared__ float Bs[KT][BN];

    const int tid = threadIdx.x;
    const int tx = tid & 15;       // col-slice owner (16)
    const int ty = tid >> 4;       // row-slice owner (16)
    const int rowbase = blockIdx.x * BM;
    const int colbase = blockIdx.y * MC;

    const int lm = tid >> 1;       // 0..127: which row of the tile this thread stages
    const int lh = tid & 1;        // which 8-float half of the k-slab

    float bestv[8];
    int   besti[8];
#pragma unroll
    for (int r = 0; r < 8; ++r) { bestv[r] = 3.4e38f; besti[r] = 0; }

    const float* gA = xb + (size_t)(rowbase + lm) * KF + lh * 8;

    for (int ct = 0; ct < COLTILES; ++ct) {
        const float* gB = wt + (size_t)(colbase + ct * BN + lm) * KF + lh * 8;

        float acc[8][8];
#pragma unroll
        for (int r = 0; r < 8; ++r)
#pragma unroll
            for (int c = 0; c < 8; ++c) acc[r][c] = 0.0f;

        // prefetch k-tile 0
        float4 a0 = *reinterpret_cast<const float4*>(gA + 0);
        float4 a1 = *reinterpret_cast<const float4*>(gA + 4);
        float4 b0 = *reinterpret_cast<const float4*>(gB + 0);
        float4 b1 = *reinterpret_cast<const float4*>(gB + 4);

        for (int k0 = 0; k0 < KF; k0 += KT) {
            __syncthreads();   // previous compute done before overwrite
            As[lh * 8 + 0][lm] = a0.x; As[lh * 8 + 1][lm] = a0.y;
            As[lh * 8 + 2][lm] = a0.z; As[lh * 8 + 3][lm] = a0.w;
            As[lh * 8 + 4][lm] = a1.x; As[lh * 8 + 5][lm] = a1.y;
            As[lh * 8 + 6][lm] = a1.z; As[lh * 8 + 7][lm] = a1.w;
            Bs[lh * 8 + 0][lm] = b0.x; Bs[lh * 8 + 1][lm] = b0.y;
            Bs[lh * 8 + 2][lm] = b0.z; Bs[lh * 8 + 3][lm] = b0.w;
            Bs[lh * 8 + 4][lm] = b1.x; Bs[lh * 8 + 5][lm] = b1.y;
            Bs[lh * 8 + 6][lm] = b1.z; Bs[lh * 8 + 7][lm] = b1.w;
            __syncthreads();

            // prefetch next k-tile (overlaps with compute below)
            if (k0 + KT < KF) {
                a0 = *reinterpret_cast<const float4*>(gA + k0 + KT);
                a1 = *reinterpret_cast<const float4*>(gA + k0 + KT + 4);
                b0 = *reinterpret_cast<const float4*>(gB + k0 + KT);
                b1 = *reinterpret_cast<const float4*>(gB + k0 + KT + 4);
            }

#pragma unroll
            for (int k = 0; k < KT; ++k) {
                const float4 av0 = *reinterpret_cast<const float4*>(&As[k][ty * 8]);
                const float4 av1 = *reinterpret_cast<const float4*>(&As[k][ty * 8 + 4]);
                const float4 bv0 = *reinterpret_cast<const float4*>(&Bs[k][tx * 8]);
                const float4 bv1 = *reinterpret_cast<const float4*>(&Bs[k][tx * 8 + 4]);
                const float ar[8] = {av0.x, av0.y, av0.z, av0.w, av1.x, av1.y, av1.z, av1.w};
                const float br[8] = {bv0.x, bv0.y, bv0.z, bv0.w, bv1.x, bv1.y, bv1.z, bv1.w};
#pragma unroll
                for (int r = 0; r < 8; ++r)
#pragma unroll
                    for (int c = 0; c < 8; ++c)
                        acc[r][c] = fmaf(ar[r], br[c], acc[r][c]);
            }
        }

        // epilogue for this col-tile: score = w_sq - 2*dot, update running argmin
#pragma unroll
        for (int c = 0; c < 8; ++c) {
            const int col = colbase + ct * BN + tx * 8 + c;
            const float wq = wsq[col];
#pragma unroll
            for (int r = 0; r < 8; ++r) {
                const float s = wq - 2.0f * acc[r][c];
                if (s < bestv[r] || (s == bestv[r] && col < besti[r])) {
                    bestv[r] = s; besti[r] = col;
                }
            }
        }
    }

    // block-level reduction across the 16 col-owning threads per row
    __syncthreads();
    float* Vs = &As[0][0];            // 128 x 16 floats (8 KB)
    int*   Is = reinterpret_cast<int*>(&Bs[0][0]);
#pragma unroll
    for (int r = 0; r < 8; ++r) {
        Vs[(ty * 8 + r) * 16 + tx] = bestv[r];
        Is[(ty * 8 + r) * 16 + tx] = besti[r];
    }
    __syncthreads();
    if (tid < BM) {
        float bv = Vs[tid * 16];
        int   bi = Is[tid * 16];
#pragma unroll
        for (int j = 1; j < 16; ++j) {
            const float v = Vs[tid * 16 + j];
            const int   i2 = Is[tid * 16 + j];
            if (v < bv || (v == bv && i2 < bi)) { bv = v; bi = i2; }
        }
        // monotone float->uint key; pack with idx so u64-min == (min val, then min idx)
        const unsigned int fb = __float_as_uint(bv);
        const unsigned int key = (fb & 0x80000000u) ? ~fb : (fb | 0x80000000u);
        part[(size_t)blockIdx.y * B_ROWS + rowbase + tid] =
            ((unsigned long long)key << 32) | (unsigned int)bi;
    }
}

// ---------------- kernel 3: reduce chunks + decode ----------------
__global__ __launch_bounds__(256) void som_decode(const unsigned long long* __restrict__ part,
                                                  int* __restrict__ out) {
    const int row = blockIdx.x * 256 + threadIdx.x;
    if (row >= B_ROWS) return;
    unsigned long long best = part[row];
#pragma unroll
    for (int c = 1; c < NCHUNK; ++c) {
        const unsigned long long p = part[(size_t)c * B_ROWS + row];
        if (p < best) best = p;
    }
    const int idx = (int)(best & 0xFFFFFFFFu);
    out[2 * row]     = idx >> 7;    // idx / 128
    out[2 * row + 1] = idx & 127;   // idx % 128
}

extern "C" void kernel_launch(void* const* d_in, const int* in_sizes, int n_in,
                              void* d_out, int out_size, void* d_ws, size_t ws_size,
                              hipStream_t stream) {
    const float* xb = (const float*)d_in[0];       // [4096, 256]
    const float* wt = (const float*)d_in[1];       // [128, 128, 256] -> [16384, 256]
    int* out = (int*)d_out;                        // [4096, 2] int32

    unsigned long long* part = (unsigned long long*)d_ws;                  // 16*4096*8 = 512 KB
    float* wsq = (float*)((char*)d_ws + (size_t)NCHUNK * B_ROWS * 8);      // 64 KB

    som_wsq<<<4096, 256, 0, stream>>>(wt, wsq);
    som_main<<<dim3(B_ROWS / BM, NCHUNK), 256, 0, stream>>>(xb, wt, wsq, part);
    som_decode<<<16, 256, 0, stream>>>(part, out);
}

// Round 2
// 196.885 us; speedup vs baseline: 2.2810x; 2.2810x over previous
//
#include <hip/hip_runtime.h>

// SOM BMU search: argmin_m (w_sq[m] - 2 * dot(x, w[m])) -> (idx/128, idx%128).
// fp32 inputs split into f16 hi/lo pairs; dot computed with 3 f16 MFMAs
// (hi*hi + hi*lo + lo*hi), fp32 accumulate -> fp32-accurate argmin on matrix cores.

#define B_ROWS 4096
#define M_COLS 16384
#define KF 256
#define BM 128
#define BN 128
#define BK 32
#define NCHUNK 16
#define MC (M_COLS / NCHUNK)   // 1024 cols per block
#define COLTILES (MC / BN)     // 8

typedef _Float16 f16x8 __attribute__((ext_vector_type(8)));
typedef _Float16 f16x4 __attribute__((ext_vector_type(4)));
typedef float f32x4 __attribute__((ext_vector_type(4)));
typedef unsigned long long u64;

#define GLOAD_LDS16(gsrc, ldst) \
  __builtin_amdgcn_global_load_lds((const __attribute__((address_space(1))) void*)(gsrc), \
                                   (__attribute__((address_space(3))) void*)(ldst), 16, 0, 0)

// ---------------- kernel 1: split W into f16 hi/lo + w_sq (fp32) ----------------
__global__ __launch_bounds__(256) void som_split_w(const float* __restrict__ wt,
                                                   _Float16* __restrict__ whi,
                                                   _Float16* __restrict__ wlo,
                                                   float* __restrict__ wsq) {
    const int row = (blockIdx.x * 256 + threadIdx.x) >> 6;   // one wave per codebook row
    const int lane = threadIdx.x & 63;
    const float4 v = *reinterpret_cast<const float4*>(wt + (size_t)row * KF + lane * 4);
    float s = v.x * v.x + v.y * v.y + v.z * v.z + v.w * v.w;
    f16x4 h, l;
    h[0] = (_Float16)v.x; l[0] = (_Float16)(v.x - (float)h[0]);
    h[1] = (_Float16)v.y; l[1] = (_Float16)(v.y - (float)h[1]);
    h[2] = (_Float16)v.z; l[2] = (_Float16)(v.z - (float)h[2]);
    h[3] = (_Float16)v.w; l[3] = (_Float16)(v.w - (float)h[3]);
    *reinterpret_cast<f16x4*>(whi + (size_t)row * KF + lane * 4) = h;
    *reinterpret_cast<f16x4*>(wlo + (size_t)row * KF + lane * 4) = l;
#pragma unroll
    for (int off = 32; off > 0; off >>= 1) s += __shfl_down(s, off, 64);
    if (lane == 0) wsq[row] = s;
}

// ---------------- kernel 2: split X into f16 hi/lo ----------------
__global__ __launch_bounds__(256) void som_split_x(const float* __restrict__ xb,
                                                   _Float16* __restrict__ xhi,
                                                   _Float16* __restrict__ xlo) {
    const int row = (blockIdx.x * 256 + threadIdx.x) >> 6;
    const int lane = threadIdx.x & 63;
    const float4 v = *reinterpret_cast<const float4*>(xb + (size_t)row * KF + lane * 4);
    f16x4 h, l;
    h[0] = (_Float16)v.x; l[0] = (_Float16)(v.x - (float)h[0]);
    h[1] = (_Float16)v.y; l[1] = (_Float16)(v.y - (float)h[1]);
    h[2] = (_Float16)v.z; l[2] = (_Float16)(v.z - (float)h[2]);
    h[3] = (_Float16)v.w; l[3] = (_Float16)(v.w - (float)h[3]);
    *reinterpret_cast<f16x4*>(xhi + (size_t)row * KF + lane * 4) = h;
    *reinterpret_cast<f16x4*>(xlo + (size_t)row * KF + lane * 4) = l;
}

// ---------------- kernel 3: MFMA GEMM + fused argmin ----------------
__global__ __launch_bounds__(256) void som_main(const _Float16* __restrict__ xhi,
                                                const _Float16* __restrict__ xlo,
                                                const _Float16* __restrict__ whi,
                                                const _Float16* __restrict__ wlo,
                                                const float* __restrict__ wsq,
                                                u64* __restrict__ part) {
    __shared__ _Float16 Ah[BM * BK];   // [128][32] row-major, 8 KB
    __shared__ _Float16 Al[BM * BK];
    __shared__ _Float16 Bh[BN * BK];
    __shared__ _Float16 Bl[BN * BK];
    __shared__ u64 red[BM][2];

    const int tid = threadIdx.x;
    const int lane = tid & 63;
    const int wid = tid >> 6;
    const int wr = wid >> 1;         // wave row (0..1), owns 64 rows
    const int wc = wid & 1;          // wave col (0..1), owns 64 cols
    const int frow = lane & 15;      // fragment row/col within 16
    const int kch = lane >> 4;       // k-chunk (8 halves each)

    const int rowbase = blockIdx.x * BM;
    const int colbase0 = blockIdx.y * MC;

    u64 best[16];
#pragma unroll
    for (int i = 0; i < 16; ++i) best[i] = ~0ull;

    for (int ct = 0; ct < COLTILES; ++ct) {
        const int colbase = colbase0 + ct * BN;

        f32x4 acc[4][4];
#pragma unroll
        for (int m = 0; m < 4; ++m)
#pragma unroll
            for (int n = 0; n < 4; ++n) acc[m][n] = (f32x4){0.f, 0.f, 0.f, 0.f};

        for (int k0 = 0; k0 < KF; k0 += BK) {
            // stage 4 tiles (A hi/lo, B hi/lo), 8 KB each, via global_load_lds x16
#pragma unroll
            for (int j = 0; j < 2; ++j) {
                const int e = j * 256 + tid;            // 16B element index
                const int eb = j * 256 + (tid & 192);   // wave-uniform LDS base element
                const int rr = e >> 2;                  // tile row
                const int kc = (e & 3) << 3;            // k offset (halves)
                const size_t ga = (size_t)(rowbase + rr) * KF + k0 + kc;
                const size_t gb = (size_t)(colbase + rr) * KF + k0 + kc;
                GLOAD_LDS16(xhi + ga, &Ah[eb * 8]);
                GLOAD_LDS16(xlo + ga, &Al[eb * 8]);
                GLOAD_LDS16(whi + gb, &Bh[eb * 8]);
                GLOAD_LDS16(wlo + gb, &Bl[eb * 8]);
            }
            __syncthreads();   // drains vmcnt: tiles ready

            f16x8 ah[4], al[4], bh[4], bl[4];
#pragma unroll
            for (int m = 0; m < 4; ++m) {
                const int r = (wr * 64 + m * 16 + frow) * BK + kch * 8;
                ah[m] = *reinterpret_cast<const f16x8*>(&Ah[r]);
                al[m] = *reinterpret_cast<const f16x8*>(&Al[r]);
            }
#pragma unroll
            for (int n = 0; n < 4; ++n) {
                const int c = (wc * 64 + n * 16 + frow) * BK + kch * 8;
                bh[n] = *reinterpret_cast<const f16x8*>(&Bh[c]);
                bl[n] = *reinterpret_cast<const f16x8*>(&Bl[c]);
            }

#pragma unroll
            for (int m = 0; m < 4; ++m)
#pragma unroll
                for (int n = 0; n < 4; ++n) {
                    acc[m][n] = __builtin_amdgcn_mfma_f32_16x16x32_f16(ah[m], bh[n], acc[m][n], 0, 0, 0);
                    acc[m][n] = __builtin_amdgcn_mfma_f32_16x16x32_f16(ah[m], bl[n], acc[m][n], 0, 0, 0);
                    acc[m][n] = __builtin_amdgcn_mfma_f32_16x16x32_f16(al[m], bh[n], acc[m][n], 0, 0, 0);
                }
            __syncthreads();   // compute done before next-tile overwrite
        }

        // epilogue for this col-tile: score = w_sq - 2*dot, update running argmin.
        // C/D layout: col = lane&15, row = (lane>>4)*4 + reg   [m89/m91 verified]
#pragma unroll
        for (int n = 0; n < 4; ++n) {
            const int colg = colbase + wc * 64 + n * 16 + frow;
            const float wq = wsq[colg];
#pragma unroll
            for (int m = 0; m < 4; ++m)
#pragma unroll
                for (int r = 0; r < 4; ++r) {
                    const float sc = wq - 2.0f * acc[m][n][r];
                    const unsigned int fb = __float_as_uint(sc);
                    const unsigned int key = (fb & 0x80000000u) ? ~fb : (fb | 0x80000000u);
                    const u64 p = ((u64)key << 32) | (unsigned int)colg;
                    if (p < best[m * 4 + r]) best[m * 4 + r] = p;
                }
        }
    }

    // reduce across the 16 col-lanes of each 16-lane group
#pragma unroll
    for (int i = 0; i < 16; ++i) {
        u64 b = best[i];
#pragma unroll
        for (int mk = 1; mk <= 8; mk <<= 1) {
            const u64 o = __shfl_xor(b, mk, 64);
            if (o < b) b = o;
        }
        best[i] = b;
    }
    if ((lane & 15) == 0) {
        const int g = lane >> 4;
#pragma unroll
        for (int m = 0; m < 4; ++m)
#pragma unroll
            for (int r = 0; r < 4; ++r)
                red[wr * 64 + m * 16 + g * 4 + r][wc] = best[m * 4 + r];
    }
    __syncthreads();
    if (tid < BM) {
        u64 a = red[tid][0];
        const u64 b2 = red[tid][1];
        if (b2 < a) a = b2;
        part[(size_t)blockIdx.y * B_ROWS + rowbase + tid] = a;
    }
}

// ---------------- kernel 4: reduce chunks + decode ----------------
__global__ __launch_bounds__(256) void som_decode(const u64* __restrict__ part,
                                                  int* __restrict__ out) {
    const int row = blockIdx.x * 256 + threadIdx.x;
    if (row >= B_ROWS) return;
    u64 best = part[row];
#pragma unroll
    for (int c = 1; c < NCHUNK; ++c) {
        const u64 p = part[(size_t)c * B_ROWS + row];
        if (p < best) best = p;
    }
    const int idx = (int)(best & 0xFFFFFFFFu);
    out[2 * row] = idx >> 7;      // idx / 128
    out[2 * row + 1] = idx & 127; // idx % 128
}

extern "C" void kernel_launch(void* const* d_in, const int* in_sizes, int n_in,
                              void* d_out, int out_size, void* d_ws, size_t ws_size,
                              hipStream_t stream) {
    const float* xb = (const float*)d_in[0];   // [4096, 256] fp32
    const float* wt = (const float*)d_in[1];   // [16384, 256] fp32
    int* out = (int*)d_out;                    // [4096, 2] int32

    char* ws = (char*)d_ws;
    _Float16* whi = (_Float16*)(ws);                                   // 8 MB
    _Float16* wlo = (_Float16*)(ws + (size_t)8 * 1024 * 1024);         // 8 MB
    _Float16* xhi = (_Float16*)(ws + (size_t)16 * 1024 * 1024);        // 2 MB
    _Float16* xlo = (_Float16*)(ws + (size_t)18 * 1024 * 1024);        // 2 MB
    float*    wsq = (float*)(ws + (size_t)20 * 1024 * 1024);           // 64 KB
    u64*     part = (u64*)(ws + (size_t)20 * 1024 * 1024 + 65536);     // 512 KB

    som_split_w<<<M_COLS / 4, 256, 0, stream>>>(wt, whi, wlo, wsq);
    som_split_x<<<B_ROWS / 4, 256, 0, stream>>>(xb, xhi, xlo);
    som_main<<<dim3(B_ROWS / BM, NCHUNK), 256, 0, stream>>>(xhi, xlo, whi, wlo, wsq, part);
    som_decode<<<B_ROWS / 256, 256, 0, stream>>>(part, out);
}

// Round 3
// 117.687 us; speedup vs baseline: 3.8160x; 1.6730x over previous
//
#include <hip/hip_runtime.h>

// SOM BMU: argmin_m (w_sq[m] - 2*dot(x,w[m])) -> (idx/128, idx%128).
// f16 hi/lo split (3 MFMAs per fp32 product), tile-major intermediate layout
// (conflict-free LDS), 2-phase double-buffered pipeline, atomicMin(u64) argmin.

#define B_ROWS 4096
#define M_COLS 16384
#define KF 256
#define BM 128
#define BN 128
#define BK 32
#define NCHUNK 16
#define NSTEP 64          // 8 col-tiles * 8 k-steps

typedef _Float16 f16x8 __attribute__((ext_vector_type(8)));
typedef float f32x4 __attribute__((ext_vector_type(4)));
typedef unsigned long long u64;

#define GLOAD16(gsrc, ldst) \
  __builtin_amdgcn_global_load_lds((const __attribute__((address_space(1))) void*)(gsrc), \
                                   (__attribute__((address_space(3))) void*)(ldst), 16, 0, 0)

// tile-major element index: tiles of 128 rows; per (tile,ks): [kch=4][r=128][kk=8] = 8KB
__device__ __forceinline__ size_t tm_idx(int tile, int ks, int kch, int r) {
    return ((((size_t)(tile * 8 + ks)) * 4 + kch) * 128 + r) * 8;
}

// ---------------- kernel 1: split W -> tile-major f16 hi/lo + w_sq ----------------
__global__ __launch_bounds__(256) void som_split_w(const float* __restrict__ wt,
                                                   _Float16* __restrict__ whi,
                                                   _Float16* __restrict__ wlo,
                                                   float* __restrict__ wsq) {
    const int gid = blockIdx.x * 256 + threadIdx.x;
    const int row = gid >> 5;          // 32 threads per row
    const int kg = gid & 31;           // 8-element k-group
    const float4 v0 = *reinterpret_cast<const float4*>(wt + (size_t)row * KF + kg * 8);
    const float4 v1 = *reinterpret_cast<const float4*>(wt + (size_t)row * KF + kg * 8 + 4);
    const float vv[8] = {v0.x, v0.y, v0.z, v0.w, v1.x, v1.y, v1.z, v1.w};
    f16x8 h, l;
    float s = 0.0f;
#pragma unroll
    for (int j = 0; j < 8; ++j) {
        h[j] = (_Float16)vv[j];
        l[j] = (_Float16)(vv[j] - (float)h[j]);
        s += vv[j] * vv[j];
    }
    const size_t e = tm_idx(row >> 7, kg >> 2, kg & 3, row & 127);
    *reinterpret_cast<f16x8*>(whi + e) = h;
    *reinterpret_cast<f16x8*>(wlo + e) = l;
#pragma unroll
    for (int off = 16; off > 0; off >>= 1) s += __shfl_down(s, off, 64);
    if (kg == 0) wsq[row] = s;   // valid in lanes 0 and 32 (one row each)
}

// ---------------- kernel 2: split X -> tile-major f16 hi/lo; init part ----------------
__global__ __launch_bounds__(256) void som_split_x(const float* __restrict__ xb,
                                                   _Float16* __restrict__ xhi,
                                                   _Float16* __restrict__ xlo,
                                                   u64* __restrict__ part) {
    const int gid = blockIdx.x * 256 + threadIdx.x;
    if (gid < B_ROWS) part[gid] = ~0ull;
    const int row = gid >> 5;
    const int kg = gid & 31;
    const float4 v0 = *reinterpret_cast<const float4*>(xb + (size_t)row * KF + kg * 8);
    const float4 v1 = *reinterpret_cast<const float4*>(xb + (size_t)row * KF + kg * 8 + 4);
    const float vv[8] = {v0.x, v0.y, v0.z, v0.w, v1.x, v1.y, v1.z, v1.w};
    f16x8 h, l;
#pragma unroll
    for (int j = 0; j < 8; ++j) {
        h[j] = (_Float16)vv[j];
        l[j] = (_Float16)(vv[j] - (float)h[j]);
    }
    const size_t e = tm_idx(row >> 7, kg >> 2, kg & 3, row & 127);
    *reinterpret_cast<f16x8*>(xhi + e) = h;
    *reinterpret_cast<f16x8*>(xlo + e) = l;
}

// ---------------- kernel 3: MFMA GEMM + fused argmin ----------------
__global__ __launch_bounds__(256, 2) void som_main(const _Float16* __restrict__ xhi,
                                                   const _Float16* __restrict__ xlo,
                                                   const _Float16* __restrict__ whi,
                                                   const _Float16* __restrict__ wlo,
                                                   const float* __restrict__ wsq,
                                                   u64* __restrict__ part) {
    __shared__ _Float16 lds[2][4][4096];   // [buf][Ah,Al,Bh,Bl][kch=4][r=128][kk=8], 64 KB

    const int tid = threadIdx.x;
    const int lane = tid & 63;
    const int frow = lane & 15;
    const int kch = lane >> 4;
    const int wid = tid >> 6;
    const int wr = wid >> 1;      // wave row (0..1): 64 rows
    const int wc = wid & 1;       // wave col (0..1): 64 cols

    // bijective XCD swizzle (512 blocks, 512%8==0): cluster same-chunk blocks per XCD
    const int id = blockIdx.x;
    const int swz = (id & 7) * 64 + (id >> 3);
    const int bx = swz & 31;      // row tile (0..31)
    const int by = swz >> 5;      // col chunk (0..15)
    const int rowbase = bx * BM;

    const int ebase = (tid & 192) * 8;   // wave-uniform LDS base (halves), round 0
    const int tid8 = tid * 8;

    u64 best[16];
#pragma unroll
    for (int i = 0; i < 16; ++i) best[i] = ~0ull;

    f32x4 acc[4][4];

#define STAGE(buf_, step_) do {                                               \
    const int ct_ = (step_) >> 3, ks_ = (step_) & 7;                          \
    const size_t ab_ = (size_t)(bx * 8 + ks_) * 4096;                         \
    const size_t bb_ = (size_t)((by * 8 + ct_) * 8 + ks_) * 4096;             \
    GLOAD16(xhi + ab_ + tid8,        &lds[buf_][0][ebase]);                   \
    GLOAD16(xhi + ab_ + 2048 + tid8, &lds[buf_][0][2048 + ebase]);            \
    GLOAD16(xlo + ab_ + tid8,        &lds[buf_][1][ebase]);                   \
    GLOAD16(xlo + ab_ + 2048 + tid8, &lds[buf_][1][2048 + ebase]);            \
    GLOAD16(whi + bb_ + tid8,        &lds[buf_][2][ebase]);                   \
    GLOAD16(whi + bb_ + 2048 + tid8, &lds[buf_][2][2048 + ebase]);            \
    GLOAD16(wlo + bb_ + tid8,        &lds[buf_][3][ebase]);                   \
    GLOAD16(wlo + bb_ + 2048 + tid8, &lds[buf_][3][2048 + ebase]);            \
  } while (0)

    STAGE(0, 0);
    int buf = 0;

    for (int step = 0; step < NSTEP; ++step) {
        __syncthreads();   // stage(step) landed; everyone done reading buf^1
        if (step < NSTEP - 1) STAGE(buf ^ 1, step + 1);

        if ((step & 7) == 0) {
#pragma unroll
            for (int m = 0; m < 4; ++m)
#pragma unroll
                for (int n = 0; n < 4; ++n) acc[m][n] = (f32x4){0.f, 0.f, 0.f, 0.f};
        }

        // B fragments (conflict-free: 16 frow lanes read a contiguous 256B line)
        f16x8 bh[4], bl[4];
#pragma unroll
        for (int n = 0; n < 4; ++n) {
            const int off = kch * 1024 + (wc * 64 + n * 16 + frow) * 8;
            bh[n] = *reinterpret_cast<const f16x8*>(&lds[buf][2][off]);
            bl[n] = *reinterpret_cast<const f16x8*>(&lds[buf][3][off]);
        }
#pragma unroll
        for (int m = 0; m < 4; ++m) {
            const int off = kch * 1024 + (wr * 64 + m * 16 + frow) * 8;
            const f16x8 ah = *reinterpret_cast<const f16x8*>(&lds[buf][0][off]);
            const f16x8 al = *reinterpret_cast<const f16x8*>(&lds[buf][1][off]);
#pragma unroll
            for (int n = 0; n < 4; ++n) {
                acc[m][n] = __builtin_amdgcn_mfma_f32_16x16x32_f16(ah, bh[n], acc[m][n], 0, 0, 0);
                acc[m][n] = __builtin_amdgcn_mfma_f32_16x16x32_f16(ah, bl[n], acc[m][n], 0, 0, 0);
                acc[m][n] = __builtin_amdgcn_mfma_f32_16x16x32_f16(al, bh[n], acc[m][n], 0, 0, 0);
            }
        }

        if ((step & 7) == 7) {
            // epilogue for finished col-tile; C/D: col=lane&15, row=(lane>>4)*4+reg
            const int colbase = by * 1024 + (step >> 3) * 128;
#pragma unroll
            for (int n = 0; n < 4; ++n) {
                const int colg = colbase + wc * 64 + n * 16 + frow;
                const float wq = wsq[colg];
#pragma unroll
                for (int m = 0; m < 4; ++m)
#pragma unroll
                    for (int r = 0; r < 4; ++r) {
                        const float sc = wq - 2.0f * acc[m][n][r];
                        const unsigned int fb = __float_as_uint(sc);
                        const unsigned int key = (fb & 0x80000000u) ? ~fb : (fb | 0x80000000u);
                        const u64 p = ((u64)key << 32) | (unsigned int)colg;
                        if (p < best[m * 4 + r]) best[m * 4 + r] = p;
                    }
            }
        }
        buf ^= 1;
    }

    // reduce across 16 col-lanes, then across the 2 col-waves, then atomicMin
    __syncthreads();
    u64* red = reinterpret_cast<u64*>(&lds[0][0][0]);   // [128 rows][2 wc]
#pragma unroll
    for (int i = 0; i < 16; ++i) {
        u64 b = best[i];
#pragma unroll
        for (int mk = 1; mk <= 8; mk <<= 1) {
            const u64 o = __shfl_xor(b, mk, 64);
            if (o < b) b = o;
        }
        if (frow == 0) {
            const int rl = wr * 64 + (i >> 2) * 16 + kch * 4 + (i & 3);
            red[rl * 2 + wc] = b;
        }
    }
    __syncthreads();
    if (tid < BM) {
        u64 a = red[tid * 2];
        const u64 b2 = red[tid * 2 + 1];
        if (b2 < a) a = b2;
        atomicMin(part + rowbase + tid, a);
    }
#undef STAGE
}

// ---------------- kernel 4: decode ----------------
__global__ __launch_bounds__(256) void som_decode(const u64* __restrict__ part,
                                                  int* __restrict__ out) {
    const int row = blockIdx.x * 256 + threadIdx.x;
    if (row >= B_ROWS) return;
    const int idx = (int)(part[row] & 0xFFFFFFFFu);
    out[2 * row] = idx >> 7;      // idx / 128
    out[2 * row + 1] = idx & 127; // idx % 128
}

extern "C" void kernel_launch(void* const* d_in, const int* in_sizes, int n_in,
                              void* d_out, int out_size, void* d_ws, size_t ws_size,
                              hipStream_t stream) {
    const float* xb = (const float*)d_in[0];   // [4096, 256] fp32
    const float* wt = (const float*)d_in[1];   // [16384, 256] fp32
    int* out = (int*)d_out;                    // [4096, 2] int32

    char* ws = (char*)d_ws;
    _Float16* xhi = (_Float16*)(ws);                                   // 2 MB
    _Float16* xlo = (_Float16*)(ws + (size_t)2 * 1024 * 1024);         // 2 MB
    _Float16* whi = (_Float16*)(ws + (size_t)4 * 1024 * 1024);         // 8 MB
    _Float16* wlo = (_Float16*)(ws + (size_t)12 * 1024 * 1024);        // 8 MB
    float*    wsq = (float*)(ws + (size_t)20 * 1024 * 1024);           // 64 KB
    u64*     part = (u64*)(ws + (size_t)20 * 1024 * 1024 + 65536);     // 32 KB

    som_split_w<<<(M_COLS * 32) / 256, 256, 0, stream>>>(wt, whi, wlo, wsq);
    som_split_x<<<(B_ROWS * 32) / 256, 256, 0, stream>>>(xb, xhi, xlo, part);
    som_main<<<B_ROWS / BM * NCHUNK, 256, 0, stream>>>(xhi, xlo, whi, wlo, wsq, part);
    som_decode<<<B_ROWS / 256, 256, 0, stream>>>(part, out);
}